// Round 1
// baseline (98.002 us; speedup 1.0000x reference)
//
#include <hip/hip_runtime.h>

// Problem constants (from reference): B = in_sizes[0]/840, L=40, A=21.
#define LPOS 40
#define AA   21
#define ROWF (LPOS*AA)      // 840 floats per row
#define CPOS 2              // positions per chunk
#define CF   (CPOS*AA)      // 42 floats per chunk per row
#define CF2  (CF/2)         // 21 float2 per chunk per row
#define NCH  (LPOS/CPOS)    // 20 chunks
#define ROWS 256            // rows per block
#define NTHR 256            // threads per block

__global__ __launch_bounds__(NTHR) void cm_kernel(
    const float* __restrict__ x,
    const float* __restrict__ v,
    const float* __restrict__ j,
    float* __restrict__ out)
{
    // [row][21] float2, flat-linear so staging writes are conflict-free.
    __shared__ float2 sx[ROWS * CF2];   // 43008 B

    const int tid = threadIdx.x;
    const long long row0 = (long long)blockIdx.x * ROWS;
    const float2* __restrict__ x2 = (const float2*)x;  // row stride = 420 float2

    float run = 1.0f, vsum = 0.0f, jsum = 0.0f;

    for (int c = 0; c < NCH; ++c) {
        __syncthreads();   // previous chunk's readers done before overwrite
        // ---- stage: 256 rows x 42 floats, coalesced float2 loads ----
        #pragma unroll
        for (int i = 0; i < (ROWS * CF2) / NTHR; ++i) {   // 21 iters
            const int g = tid + i * NTHR;                 // [0, 5376)
            const int r = g / CF2;                        // row in block
            const int e = g - r * CF2;                    // float2 elem
            sx[g] = x2[(row0 + r) * (ROWF / 2) + c * CF2 + e];
        }
        __syncthreads();
        // ---- compute: thread owns its row's 42 floats ----
        const float* __restrict__ xs = (const float*)&sx[tid * CF2];
        #pragma unroll
        for (int p = 0; p < CPOS; ++p) {
            const int l = c * CPOS + p;
            float m = 0.0f;
            #pragma unroll
            for (int a = 0; a < AA; ++a) {
                const float xv = xs[p * AA + a];
                m    = fmaf(xv, v[l * AA + a], m);     // uniform -> s_load
                jsum = fmaf(xv, j[l * AA + a], jsum);  // uniform -> s_load
            }
            run  *= m;       // cumprod
            vsum += run;     // sum of cumprod
        }
    }

    const long long orow = row0 + tid;
    ((float2*)out)[orow] = make_float2(vsum, jsum);   // [B,2] coalesced 8B store
}

extern "C" void kernel_launch(void* const* d_in, const int* in_sizes, int n_in,
                              void* d_out, int out_size, void* d_ws, size_t ws_size,
                              hipStream_t stream) {
    const float* x = (const float*)d_in[0];
    const float* v = (const float*)d_in[1];
    const float* j = (const float*)d_in[2];
    float* out     = (float*)d_out;

    const int B    = in_sizes[0] / ROWF;   // 131072
    const int grid = B / ROWS;             // 512 (B is a multiple of 256)

    cm_kernel<<<grid, NTHR, 0, stream>>>(x, v, j, out);
}